// Round 10
// baseline (184.090 us; speedup 1.0000x reference)
//
#include <hip/hip_runtime.h>
#include <hip/hip_bf16.h>

// Problem constants
#define BB 16
#define CC 64
#define HH 64
#define WW 64
#define QQ 8192
#define HID 256
#define KK 576            // C*9
#define HT 66             // H + 2 halo
#define FROW 264          // 257 channels padded to 264 (16B-aligned rows)

typedef short short8 __attribute__((ext_vector_type(8)));
typedef short sv4    __attribute__((ext_vector_type(4)));
typedef float f32x4  __attribute__((ext_vector_type(4)));

__device__ __forceinline__ short f2bf(float f) {
    union { float f; unsigned u; } v; v.f = f;
    unsigned r = v.u + 0x7fffu + ((v.u >> 16) & 1u);
    return (short)(r >> 16);
}
__device__ __forceinline__ float bf2f(short s) {
    union { unsigned u; float f; } v; v.u = ((unsigned)(unsigned short)s) << 16;
    return v.f;
}
// Barrier that only drains LDS (lgkmcnt) — does NOT force vmcnt(0).
__device__ __forceinline__ void barrier_lds() {
    asm volatile("s_waitcnt lgkmcnt(0)" ::: "memory");
    __builtin_amdgcn_s_barrier();
    asm volatile("" ::: "memory");
}
// Async global->LDS DMA, 16B per lane (dest = wave-uniform base + lane*16).
__device__ __forceinline__ void glld16(const short* g, short* l) {
    __builtin_amdgcn_global_load_lds(
        (const __attribute__((address_space(1))) void*)g,
        (__attribute__((address_space(3))) void*)l, 16, 0, 0);
}

// ---------------------------------------------------------------------------
// Kernel T+P fused (unchanged): feat transpose + weight repack into
// per-K-step contiguous DMA blocks:
//   w3cB[(kchunk)*2176 + n*8 + j] = w3k(n, kchunk*8+j)
//   w2cB[(kchunk)*2048 + n*8 + j] = w2[kchunk*8+j][n]
// ---------------------------------------------------------------------------
__global__ __launch_bounds__(256) void prep_transpose_k(const float* __restrict__ feat,
                                                        const float* __restrict__ w2,
                                                        const float* __restrict__ w3,
                                                        const float* __restrict__ b3,
                                                        short* __restrict__ featT,
                                                        short* __restrict__ w3cB,
                                                        short* __restrict__ w2cB) {
    __shared__ float ftile[64][65];
    const int t = threadIdx.x;
    const int gidx = blockIdx.x * 256 + t;   // grid = 1056 wgs

    if (gidx < 156672) {                      // 72 kchunks * 272 n * 8
        int kchunk = gidx / 2176;
        int rem = gidx - kchunk * 2176;
        int n = rem >> 3, j = rem & 7;
        int kglob = kchunk * 8 + j;
        int pos = kglob >> 6, c = kglob & 63;
        float v = 0.f;
        if (n < 256)      v = w3[n * KK + c * 9 + pos];
        else if (n == 256) v = b3[c * 9 + pos];
        w3cB[gidx] = f2bf(v);
    }
    if (gidx < 65536) {                       // 32 kchunks * 256 n * 8
        int kchunk = gidx >> 11;
        int rem = gidx & 2047;
        int n = rem >> 3, j = rem & 7;
        int k = kchunk * 8 + j;
        w2cB[gidx] = f2bf(w2[k * 256 + n]);
    }

    const int b = blockIdx.x / HT;
    const int yy = blockIdx.x - b * HT;
    short* out_row = featT + ((b * HT + yy) * HT) * 64;

    if (yy == 0 || yy == HT - 1) {
        for (int idx = t; idx < HT * 64; idx += 256) out_row[idx] = 0;
        return;
    }
    const int y = yy - 1;
    const float* src = feat + ((b * CC) * HH + y) * WW;
#pragma unroll
    for (int i = 0; i < 16; ++i) {
        int idx = i * 256 + t;
        int c = idx >> 6, x = idx & 63;
        ftile[c][x] = src[c * (HH * WW) + x];
    }
    if (t < 64) out_row[t] = 0;
    else if (t < 128) out_row[(HT - 1) * 64 + (t - 64)] = 0;
    __syncthreads();
#pragma unroll
    for (int i = 0; i < 16; ++i) {
        int idx = i * 256 + t;
        int x = idx >> 6, c = idx & 63;
        out_row[(x + 1) * 64 + c] = f2bf(ftile[c][x]);
    }
}

// ---------------------------------------------------------------------------
// Kernel C v7: 512 threads, M=128 (y-pair). Grid = 512 wgs = exactly 2/CU ->
// whole conv is one resident generation. The two output rows share one
// 4-row input slab (38 KB, vs 2x28.5 for separate wgs).
//   8 waves: mh = wave>>2 selects output row, nq = wave&3 selects n-subtiles
//   {nq+4i} + redundant subtile 16 (only nq==0 stores it).
//   Per k-step: DMA next 17.4 KB B-tile (double-buffered) while MFMAs consume
//   current; af/bf via ds_read_b128.
// ---------------------------------------------------------------------------
#define SSTR 72   // slab row stride (shorts)
__global__ __launch_bounds__(512, 4) void conv_k(const short* __restrict__ featT,
                                                 const short* __restrict__ w3cB,
                                                 short* __restrict__ F) {
    __shared__ short slab[4 * HT * SSTR];   // 19,008 shorts = 38,016 B
    __shared__ short Bb[2][8704];           // 2 x 17,408 B
    const int t = threadIdx.x;
    const int wave = t >> 6, lane = t & 63, quad = lane >> 4, ln16 = lane & 15;
    const int mh = wave >> 2, nq = wave & 3;
    const int b = blockIdx.x >> 5;
    const int y0 = (blockIdx.x & 31) * 2;

    f32x4 acc[4][5];
#pragma unroll
    for (int a = 0; a < 4; ++a)
#pragma unroll
        for (int i = 0; i < 5; ++i) acc[a][i] = (f32x4){0.f, 0.f, 0.f, 0.f};

    auto stageB = [&](int buf, int st) {
        const short* src = w3cB + st * 8704;
#pragma unroll
        for (int u = 0; u < 2; ++u) {
            int cidx = u * 8 + wave;
            glld16(src + cidx * 512 + lane * 8, &Bb[buf][cidx * 512]);
        }
        if (wave == 0)
            glld16(src + 16 * 512 + lane * 8, &Bb[buf][16 * 512]);
    };

    stageB(0, 0);   // DMA in flight during slab staging

    // Stage slab: featT rows y0..y0+3 contiguous (4*66*64 = 16896 shorts)
    const short* slabsrc = featT + b * (HT * HT * 64) + y0 * (HT * 64);
#pragma unroll
    for (int it = 0; it < 5; ++it) {
        int i = it * 512 + t;               // 2112 chunks of 8 shorts
        if (i < 2112) {
            short8 v = *(const short8*)(slabsrc + i * 8);
            *(short8*)(&slab[(i >> 3) * SSTR + (i & 7) * 8]) = v;
        }
    }
    __syncthreads();   // drains slab stores (lgkm) + B DMA (vmcnt)

#pragma unroll
    for (int st = 0; st < 18; ++st) {
        const int cur = st & 1;
        if (st < 17) stageB(cur ^ 1, st + 1);
        const int pos = st >> 1, ks = st & 1;
        const int di = pos / 3, dj = pos - di * 3;
        short8 af[4];
#pragma unroll
        for (int ms = 0; ms < 4; ++ms)
            af[ms] = *(const short8*)(&slab[((mh + di) * HT + ms * 16 + ln16 + dj) * SSTR + ks * 32 + quad * 8]);
#pragma unroll
        for (int i = 0; i < 5; ++i) {
            int sub = (i < 4) ? (nq + 4 * i) : 16;
            short8 bf = *(const short8*)(&Bb[cur][(quad * 272 + sub * 16 + ln16) * 8]);
#pragma unroll
            for (int ms = 0; ms < 4; ++ms)
                acc[ms][i] = __builtin_amdgcn_mfma_f32_16x16x32_bf16(af[ms], bf, acc[ms][i], 0, 0, 0);
        }
        __syncthreads();   // Bb[cur] reads done; next step's DMA may reuse it
    }

    // Epilogue: per output row (h = mh), scatter into 64xFROW LDS (reusing
    // slab), then full-line coalesced copy.
#pragma unroll
    for (int h = 0; h < 2; ++h) {
        if (mh == h) {
#pragma unroll
            for (int i = 0; i < 5; ++i) {
                int sub = (i < 4) ? (nq + 4 * i) : 16;
                int n = sub * 16 + ln16;
                bool store = (i < 4) || (nq == 0 && n < FROW);
                if (store) {
#pragma unroll
                    for (int ms = 0; ms < 4; ++ms)
#pragma unroll
                        for (int r = 0; r < 4; ++r) {
                            int xl = ms * 16 + quad * 4 + r;   // local x 0..63
                            slab[xl * FROW + n] = f2bf(acc[ms][i][r]);
                        }
                }
            }
        }
        __syncthreads();
        short8* dst = (short8*)(F + (long)((b * 64 + y0 + h) * 64) * FROW);
        const short8* src8 = (const short8*)slab;
#pragma unroll
        for (int it = 0; it < 5; ++it) {
            int idx = it * 512 + t;
            if (idx < (64 * FROW) / 8) dst[idx] = src8[idx];
        }
        __syncthreads();
    }
}

// ---------------------------------------------------------------------------
// Kernel M v8: 512 threads, 128 queries/wg (grid 1024). 8 waves:
//   mh = wave>>2 -> query half [mh*64, +64); nq = wave&3 -> n-slice [nq*64,+64)
//   Thread computes coords+H1 for query mh*64+lane on k-slice nq*64 (64 vals,
//   regs). K-split Hh[128][136]: nq<2 write k<128 before loop; nq>=2 write
//   k>=128 at the s=3 barrier. w2 DMA double-buffered (16 KB/step).
//   LDS ~70 KB -> 2 wg/CU = 16 waves/CU.
// ---------------------------------------------------------------------------
#define HSPLIT 136   // 272B rows, 16B-aligned
__global__ __launch_bounds__(512, 4) void mlp_k(const float* __restrict__ coord,
                                                const float* __restrict__ cell,
                                                const float* __restrict__ w1,
                                                const float* __restrict__ b1,
                                                const float* __restrict__ b2v,
                                                const short* __restrict__ w2cB,
                                                const short* __restrict__ F,
                                                float* __restrict__ out) {
    __shared__ short Hh[128 * HSPLIT];      // 34,816 B
    __shared__ short Wb[2][8192];           // 32,768 B
    __shared__ float red_s[128][4];         // 2,048 B
    __shared__ float fbv_s[128];            // 512 B

    const int t = threadIdx.x;
    const int wave = t >> 6, lane = t & 63, quad = lane >> 4, ln16 = lane & 15;
    const int mh = wave >> 2, nq = wave & 3;
    const int qbase = blockIdx.x * 128;
    const int b = blockIdx.x >> 6;          // 64 wgs per batch

    auto stageW = [&](int buf, int s) {
        const short* src = w2cB + s * 8192;
#pragma unroll
        for (int u = 0; u < 2; ++u) {
            int cidx = u * 8 + wave;
            glld16(src + cidx * 512 + lane * 8, &Wb[buf][cidx * 512]);
        }
    };

    stageW(0, 0);   // DMA in flight through coord + H1 compute

    // --- coords for own query (query = mh*64 + lane) ---
    const int g = qbase + mh * 64 + lane;
    const float2 cc = *(const float2*)(coord + g * 2);
    const float2 ce = *(const float2*)(cell + g * 2);
    const float coy = cc.x - ce.x * 0.5f, cox = cc.y - ce.y * 0.5f;
    const float cqy = fminf(fmaxf(coy + 1e-6f, -0.999999f), 0.999999f);
    const float cqx = fminf(fmaxf(cox + 1e-6f, -0.999999f), 0.999999f);
    int iy = (int)rintf(((cqy + 1.0f) * 64.0f - 1.0f) * 0.5f); iy = min(max(iy, 0), 63);
    int ix = (int)rintf(((cqx + 1.0f) * 64.0f - 1.0f) * 0.5f); ix = min(max(ix, 0), 63);
    const int lin = iy * 64 + ix;
    const float in0 = (coy - ((float)iy * (1.0f / 32.0f) - 1.0f)) * 32.0f;
    const float in1 = (cox - ((float)ix * (1.0f / 32.0f) - 1.0f)) * 32.0f;
    const float in2 = ce.x * 32.0f;

    // --- H1 for own query, k-slice [nq*64, nq*64+64) -> regs ---
    short8 hv[8];
    const int k0w = nq * 64;
#pragma unroll
    for (int c8 = 0; c8 < 8; ++c8) {
        const int k0 = k0w + c8 * 8;
        f32x4 wa0 = *(const f32x4*)(w1 + k0),       wa1 = *(const f32x4*)(w1 + k0 + 4);
        f32x4 wb0 = *(const f32x4*)(w1 + 256 + k0), wb1 = *(const f32x4*)(w1 + 256 + k0 + 4);
        f32x4 wc0 = *(const f32x4*)(w1 + 512 + k0), wc1 = *(const f32x4*)(w1 + 512 + k0 + 4);
        f32x4 bb0 = *(const f32x4*)(b1 + k0),       bb1 = *(const f32x4*)(b1 + k0 + 4);
#pragma unroll
        for (int jj = 0; jj < 4; ++jj) {
            float v0 = fmaf(in0, wa0[jj], fmaf(in1, wb0[jj], fmaf(in2, wc0[jj], bb0[jj])));
            float v1 = fmaf(in0, wa1[jj], fmaf(in1, wb1[jj], fmaf(in2, wc1[jj], bb1[jj])));
            hv[c8][jj]     = f2bf(fmaxf(v0, 0.f));
            hv[c8][jj + 4] = f2bf(fmaxf(v1, 0.f));
        }
    }
    // phase-0: nq 0/1 write k<128 slice
    if (nq < 2) {
#pragma unroll
        for (int c8 = 0; c8 < 8; ++c8)
            *(short8*)(&Hh[(mh * 64 + lane) * HSPLIT + nq * 64 + c8 * 8]) = hv[c8];
    }
    f32x4 b2q[4];
#pragma unroll
    for (int i = 0; i < 4; ++i)
        b2q[i] = *(const f32x4*)(b2v + nq * 64 + i * 16 + quad * 4);
    __syncthreads();   // drains phase-0 H writes (lgkm) + Wb(0) DMA (vmcnt)

    // --- H2^T MFMA loop ---
    f32x4 acc2[4][4];
#pragma unroll
    for (int i = 0; i < 4; ++i)
#pragma unroll
        for (int ms = 0; ms < 4; ++ms) acc2[i][ms] = (f32x4){0.f, 0.f, 0.f, 0.f};
#pragma unroll
    for (int s = 0; s < 8; ++s) {
        const int cur = s & 1;
        if (s < 7) stageW(cur ^ 1, s + 1);
        short8 wf[4], hf[4];
#pragma unroll
        for (int i = 0; i < 4; ++i)
            wf[i] = *(const short8*)(&Wb[cur][(quad * 256 + nq * 64 + i * 16 + ln16) * 8]);
        const int col = (s & 3) * 32 + quad * 8;    // k within current half
#pragma unroll
        for (int ms = 0; ms < 4; ++ms)
            hf[ms] = *(const short8*)(&Hh[(mh * 64 + ms * 16 + ln16) * HSPLIT + col]);
#pragma unroll
        for (int i = 0; i < 4; ++i)
#pragma unroll
            for (int ms = 0; ms < 4; ++ms)
                acc2[i][ms] = __builtin_amdgcn_mfma_f32_16x16x32_bf16(wf[i], hf[ms], acc2[i][ms], 0, 0, 0);
        if (s == 3) {
            __syncthreads();          // drain DMA(4); all phase-0 H reads done
            if (nq >= 2) {            // phase-1: k>=128 slice
#pragma unroll
                for (int c8 = 0; c8 < 8; ++c8)
                    *(short8*)(&Hh[(mh * 64 + lane) * HSPLIT + (nq - 2) * 64 + c8 * 8]) = hv[c8];
            }
            barrier_lds();            // phase-1 visible (lgkm only)
        } else if (s < 7) {
            __syncthreads();          // drain DMA(s+1)
        }
    }

    // --- F gather (late) ---
    const short* Fb = F + (long)b * 4096 * FROW;
    sv4 fv[4][4];
#pragma unroll
    for (int ms = 0; ms < 4; ++ms) {
        int linm = __shfl(lin, ms * 16 + ln16, 64);
        const short* Fr = Fb + (long)linm * FROW + nq * 64 + quad * 4;
#pragma unroll
        for (int i = 0; i < 4; ++i) fv[ms][i] = *(const sv4*)(Fr + i * 16);
    }

    // --- combine: pred[m] += relu(H2[n][m]+b2[n]) * F[lin[m]][n] ---
    float part[4] = {0.f, 0.f, 0.f, 0.f};
#pragma unroll
    for (int i = 0; i < 4; ++i)
#pragma unroll
        for (int ms = 0; ms < 4; ++ms)
#pragma unroll
            for (int r = 0; r < 4; ++r)
                part[ms] = fmaf(fmaxf(acc2[i][ms][r] + b2q[i][r], 0.f), bf2f(fv[ms][i][r]), part[ms]);
#pragma unroll
    for (int ms = 0; ms < 4; ++ms) {
        part[ms] += __shfl_xor(part[ms], 16, 64);
        part[ms] += __shfl_xor(part[ms], 32, 64);
    }
    if (quad == 0) {
#pragma unroll
        for (int ms = 0; ms < 4; ++ms) red_s[mh * 64 + ms * 16 + ln16][nq] = part[ms];
    }
    if (nq == 0)
        fbv_s[mh * 64 + lane] = bf2f(Fb[(long)lin * FROW + 256]);
    barrier_lds();
    if (t < 128)
        out[qbase + t] = red_s[t][0] + red_s[t][1] + red_s[t][2] + red_s[t][3] + fbv_s[t];
}

// ---------------------------------------------------------------------------
extern "C" void kernel_launch(void* const* d_in, const int* in_sizes, int n_in,
                              void* d_out, int out_size, void* d_ws, size_t ws_size,
                              hipStream_t stream) {
    const float* feat  = (const float*)d_in[0];
    const float* coord = (const float*)d_in[1];
    const float* cell  = (const float*)d_in[2];
    const float* w1    = (const float*)d_in[3];
    const float* b1    = (const float*)d_in[4];
    const float* w2    = (const float*)d_in[5];
    const float* b2    = (const float*)d_in[6];
    const float* w3    = (const float*)d_in[7];
    const float* b3    = (const float*)d_in[8];
    float* out = (float*)d_out;

    char* ws = (char*)d_ws;
    short* w3cB  = (short*)(ws);                       // 72*2176*2      = 313,344
    short* w2cB  = (short*)(ws + 313344);              // 32*2048*2      = 131,072
    short* featT = (short*)(ws + 444416);              // 16*66*66*64*2  = 8,921,088
    short* F     = (short*)(ws + 9365504);             // 16*4096*264*2  = 34,603,008
    (void)ws_size; (void)in_sizes; (void)n_in; (void)out_size;

    prep_transpose_k<<<BB * HT, 256, 0, stream>>>(feat, w2, w3, b3, featT, w3cB, w2cB);
    conv_k<<<BB * 32, 512, 0, stream>>>(featT, w3cB, F);
    mlp_k<<<(BB * QQ) / 128, 512, 0, stream>>>(coord, cell, w1, b1, b2, w2cB, F, out);
}

// Round 11
// 174.918 us; speedup vs baseline: 1.0524x; 1.0524x over previous
//
#include <hip/hip_runtime.h>
#include <hip/hip_bf16.h>

// Problem constants
#define BB 16
#define CC 64
#define HH 64
#define WW 64
#define QQ 8192
#define HID 256
#define KK 576            // C*9
#define HT 66             // H + 2 halo
#define FROW 264          // 257 channels padded to 264 (16B-aligned rows)

typedef short short8 __attribute__((ext_vector_type(8)));
typedef short sv4    __attribute__((ext_vector_type(4)));
typedef float f32x4  __attribute__((ext_vector_type(4)));

__device__ __forceinline__ short f2bf(float f) {
    union { float f; unsigned u; } v; v.f = f;
    unsigned r = v.u + 0x7fffu + ((v.u >> 16) & 1u);
    return (short)(r >> 16);
}
__device__ __forceinline__ float bf2f(short s) {
    union { unsigned u; float f; } v; v.u = ((unsigned)(unsigned short)s) << 16;
    return v.f;
}
// Barrier that only drains LDS (lgkmcnt) — does NOT force vmcnt(0).
__device__ __forceinline__ void barrier_lds() {
    asm volatile("s_waitcnt lgkmcnt(0)" ::: "memory");
    __builtin_amdgcn_s_barrier();
    asm volatile("" ::: "memory");
}
// Async global->LDS DMA, 16B per lane (dest = wave-uniform base + lane*16).
__device__ __forceinline__ void glld16(const short* g, short* l) {
    __builtin_amdgcn_global_load_lds(
        (const __attribute__((address_space(1))) void*)g,
        (__attribute__((address_space(3))) void*)l, 16, 0, 0);
}

// ---------------------------------------------------------------------------
// Kernel T+P fused: feat transpose + weight repack into per-K-step DMA blocks.
// NEW K-order for w3 (channel-half-major): kglob = khalf*288 + pos*32 + c32,
// channel c = khalf*32 + c32. This lets conv_k stage only half the channels
// of its A-slab at a time (halves slab LDS -> 3 wg/CU).
//   w3cB[kchunk*2176 + n*8 + j]: kglob = kchunk*8+j
//   w2cB[kchunk*2048 + n*8 + j] = w2[kchunk*8+j][n]
// ---------------------------------------------------------------------------
__global__ __launch_bounds__(256) void prep_transpose_k(const float* __restrict__ feat,
                                                        const float* __restrict__ w2,
                                                        const float* __restrict__ w3,
                                                        const float* __restrict__ b3,
                                                        short* __restrict__ featT,
                                                        short* __restrict__ w3cB,
                                                        short* __restrict__ w2cB) {
    __shared__ float ftile[64][65];
    const int t = threadIdx.x;
    const int gidx = blockIdx.x * 256 + t;   // grid = 1056 wgs

    if (gidx < 156672) {                      // 72 kchunks * 272 n * 8
        int kchunk = gidx / 2176;
        int rem = gidx - kchunk * 2176;
        int n = rem >> 3, j = rem & 7;
        int kglob = kchunk * 8 + j;           // new K order
        int khalf = kglob / 288;
        int r2 = kglob - khalf * 288;
        int pos = r2 >> 5;
        int c = khalf * 32 + (r2 & 31);
        float v = 0.f;
        if (n < 256)      v = w3[n * KK + c * 9 + pos];
        else if (n == 256) v = b3[c * 9 + pos];
        w3cB[gidx] = f2bf(v);
    }
    if (gidx < 65536) {                       // 32 kchunks * 256 n * 8
        int kchunk = gidx >> 11;
        int rem = gidx & 2047;
        int n = rem >> 3, j = rem & 7;
        int k = kchunk * 8 + j;
        w2cB[gidx] = f2bf(w2[k * 256 + n]);
    }

    const int b = blockIdx.x / HT;
    const int yy = blockIdx.x - b * HT;
    short* out_row = featT + ((b * HT + yy) * HT) * 64;

    if (yy == 0 || yy == HT - 1) {
        for (int idx = t; idx < HT * 64; idx += 256) out_row[idx] = 0;
        return;
    }
    const int y = yy - 1;
    const float* src = feat + ((b * CC) * HH + y) * WW;
#pragma unroll
    for (int i = 0; i < 16; ++i) {
        int idx = i * 256 + t;
        int c = idx >> 6, x = idx & 63;
        ftile[c][x] = src[c * (HH * WW) + x];
    }
    if (t < 64) out_row[t] = 0;
    else if (t < 128) out_row[(HT - 1) * 64 + (t - 64)] = 0;
    __syncthreads();
#pragma unroll
    for (int i = 0; i < 16; ++i) {
        int idx = i * 256 + t;
        int x = idx >> 6, c = idx & 63;
        out_row[(x + 1) * 64 + c] = f2bf(ftile[c][x]);
    }
}

// ---------------------------------------------------------------------------
// Kernel C v8: m97-style K-loop + channel-half A-slab for 3 wg/CU.
//   wg=(b,y): M=64, N=272, K=576; 18 steps (st = khalf*9 + pos).
//   A-slab holds 3x66 rows x 32 channels (14.3 KB), restaged once at st=9.
//   B-tile DMA double-buffered (2x17.4 KB). LDS total 49.1 KB -> 3 wg/CU;
//   (256,3) caps unified regs at the 3-wave budget (~150 needed, no spill).
// ---------------------------------------------------------------------------
#define SST2 36   // slab row stride (shorts): 32 ch + 4 pad, 72B rows
__global__ __launch_bounds__(256, 3) void conv_k(const short* __restrict__ featT,
                                                 const short* __restrict__ w3cB,
                                                 short* __restrict__ F) {
    __shared__ short SH[24536];   // [0,7128): slab | [7128,+8704): Bb0 | +8704: Bb1
    short* slab = SH;
    const int t = threadIdx.x;
    const int wave = t >> 6, lane = t & 63, quad = lane >> 4, ln16 = lane & 15;
    const int b = blockIdx.x >> 6, y = blockIdx.x & 63;

    f32x4 acc[4][5];
#pragma unroll
    for (int a = 0; a < 4; ++a)
#pragma unroll
        for (int i = 0; i < 5; ++i) acc[a][i] = (f32x4){0.f, 0.f, 0.f, 0.f};

    auto stageB = [&](int buf, int st) {
        const short* src = w3cB + st * 8704;
        short* dstb = SH + 7128 + buf * 8704;
#pragma unroll
        for (int u = 0; u < 5; ++u) {
            int cidx = (u < 4) ? (u * 4 + wave) : 16;
            if (u < 4 || wave == 0)
                glld16(src + cidx * 512 + lane * 8, dstb + cidx * 512);
        }
    };
    const short* slabsrc = featT + b * (HT * HT * 64) + y * (HT * 64);
    auto stageA = [&](int kh) {
        // 198 rows x 32 ch = 792 chunks of 8 shorts
#pragma unroll
        for (int it = 0; it < 4; ++it) {
            int i = it * 256 + t;
            if (i < 792) {
                int r = i >> 2, s = (i & 3) * 8;
                short8 v = *(const short8*)(slabsrc + r * 64 + kh * 32 + s);
                *(short8*)(&slab[r * SST2 + s]) = v;
            }
        }
    };

    stageB(0, 0);   // DMA in flight during slab staging
    stageA(0);
    __syncthreads();   // drains slab stores (lgkm) + B DMA (vmcnt)

#pragma unroll
    for (int st = 0; st < 18; ++st) {
        const int cur = st & 1;
        if (st < 17) stageB(cur ^ 1, st + 1);
        const int pos = (st < 9) ? st : (st - 9);
        const int di = pos / 3, dj = pos - di * 3;
        const short* Bc = SH + 7128 + cur * 8704;
        short8 af[4];
#pragma unroll
        for (int ms = 0; ms < 4; ++ms)
            af[ms] = *(const short8*)(&slab[(di * HT + ms * 16 + ln16 + dj) * SST2 + quad * 8]);
#pragma unroll
        for (int i = 0; i < 5; ++i) {
            int sub = (i < 4) ? (wave + 4 * i) : 16;
            short8 bf = *(const short8*)(Bc + (quad * 272 + sub * 16 + ln16) * 8);
#pragma unroll
            for (int ms = 0; ms < 4; ++ms)
                acc[ms][i] = __builtin_amdgcn_mfma_f32_16x16x32_bf16(af[ms], bf, acc[ms][i], 0, 0, 0);
        }
        if (st == 8) {
            __syncthreads();      // slab kh=0 reads done; drains DMA(9)
            stageA(1);            // restage channel-half 1
            barrier_lds();        // slab kh=1 visible (lgkm only)
        } else {
            __syncthreads();      // Bb[cur] reads done; next DMA may reuse it
        }
    }

    // Epilogue: two 32-row halves through SH, full-line stores.
#pragma unroll
    for (int h = 0; h < 2; ++h) {
#pragma unroll
        for (int i = 0; i < 5; ++i) {
            int sub = (i < 4) ? (wave + 4 * i) : 16;
            int n = sub * 16 + ln16;
            bool store = (i < 4) || (wave == 0 && n < FROW);
            if (store) {
#pragma unroll
                for (int ms2 = 0; ms2 < 2; ++ms2) {
                    int ms = h * 2 + ms2;
#pragma unroll
                    for (int r = 0; r < 4; ++r) {
                        int xl = ms2 * 16 + quad * 4 + r;   // local row 0..31
                        SH[xl * FROW + n] = f2bf(acc[ms][i][r]);
                    }
                }
            }
        }
        __syncthreads();
        short8* dst = (short8*)(F + ((long)(b * 64 + y) * 64 + h * 32) * FROW);
        const short8* src8 = (const short8*)SH;
#pragma unroll
        for (int it = 0; it < 5; ++it) {
            int idx = it * 256 + t;
            if (idx < (32 * FROW) / 8) dst[idx] = src8[idx];
        }
        __syncthreads();
    }
}

// ---------------------------------------------------------------------------
// Kernel M v9: R9 v7 + register diet for 3 waves/SIMD.
//   No persistent hv[8]: waves 0/1 compute+write H1 (k<128) before the loop;
//   waves 2/3 RECOMPUTE H1 at the s==3 barrier (~200 cyc VALU vs idle pipes,
//   w1 addresses wave-uniform -> scalar loads). Unified regs ~140 (was 168 —
//   over the 3-wave granularity edge, which is why R9's LDS cut alone
//   didn't raise occupancy). (256,3) sets the allocator budget.
//   LDS 51.2 KB; K-split Hh; double-buffered w2 DMA.
// ---------------------------------------------------------------------------
#define HSPLIT 136   // 272B rows, 16B-aligned
__global__ __launch_bounds__(256, 3) void mlp_k(const float* __restrict__ coord,
                                                const float* __restrict__ cell,
                                                const float* __restrict__ w1,
                                                const float* __restrict__ b1,
                                                const float* __restrict__ b2v,
                                                const short* __restrict__ w2cB,
                                                const short* __restrict__ F,
                                                float* __restrict__ out) {
    __shared__ short Hh[64 * HSPLIT];       // 17,408 B (half-K)
    __shared__ short Wb[2][8192];           // 32,768 B
    __shared__ float red_s[64][4];          // 1,024 B

    const int t = threadIdx.x;
    const int wave = t >> 6, lane = t & 63, quad = lane >> 4, ln16 = lane & 15;
    const int qbase = blockIdx.x * 64;
    const int b = qbase >> 13;              // Q = 8192

    auto stageW = [&](int buf, int s) {
        const short* src = w2cB + s * 8192;
#pragma unroll
        for (int u = 0; u < 4; ++u) {
            int cidx = u * 4 + wave;
            glld16(src + cidx * 512 + lane * 8, &Wb[buf][cidx * 512]);
        }
    };

    stageW(0, 0);   // DMA in flight through coord + H1 compute

    // --- coords for own query (lane = query) ---
    const int g = qbase + lane;
    const float2 cc = *(const float2*)(coord + g * 2);
    const float2 ce = *(const float2*)(cell + g * 2);
    const float coy = cc.x - ce.x * 0.5f, cox = cc.y - ce.y * 0.5f;
    const float cqy = fminf(fmaxf(coy + 1e-6f, -0.999999f), 0.999999f);
    const float cqx = fminf(fmaxf(cox + 1e-6f, -0.999999f), 0.999999f);
    int iy = (int)rintf(((cqy + 1.0f) * 64.0f - 1.0f) * 0.5f); iy = min(max(iy, 0), 63);
    int ix = (int)rintf(((cqx + 1.0f) * 64.0f - 1.0f) * 0.5f); ix = min(max(ix, 0), 63);
    const int lin = iy * 64 + ix;
    const float in0 = (coy - ((float)iy * (1.0f / 32.0f) - 1.0f)) * 32.0f;
    const float in1 = (cox - ((float)ix * (1.0f / 32.0f) - 1.0f)) * 32.0f;
    const float in2 = ce.x * 32.0f;

    // H1 for own query, k-slice [wave*64, +64), written to Hh column (wave&1)*64
    auto computeH1_write = [&]() {
        const int kbase = wave * 64;
        const int col = (wave & 1) * 64;
#pragma unroll
        for (int c8 = 0; c8 < 8; ++c8) {
            const int k0 = kbase + c8 * 8;
            f32x4 wa0 = *(const f32x4*)(w1 + k0),       wa1 = *(const f32x4*)(w1 + k0 + 4);
            f32x4 wb0 = *(const f32x4*)(w1 + 256 + k0), wb1 = *(const f32x4*)(w1 + 256 + k0 + 4);
            f32x4 wc0 = *(const f32x4*)(w1 + 512 + k0), wc1 = *(const f32x4*)(w1 + 512 + k0 + 4);
            f32x4 bb0 = *(const f32x4*)(b1 + k0),       bb1 = *(const f32x4*)(b1 + k0 + 4);
            short8 hv;
#pragma unroll
            for (int jj = 0; jj < 4; ++jj) {
                float v0 = fmaf(in0, wa0[jj], fmaf(in1, wb0[jj], fmaf(in2, wc0[jj], bb0[jj])));
                float v1 = fmaf(in0, wa1[jj], fmaf(in1, wb1[jj], fmaf(in2, wc1[jj], bb1[jj])));
                hv[jj]     = f2bf(fmaxf(v0, 0.f));
                hv[jj + 4] = f2bf(fmaxf(v1, 0.f));
            }
            *(short8*)(&Hh[lane * HSPLIT + col + c8 * 8]) = hv;
        }
    };

    if (wave < 2) computeH1_write();       // phase-0: k<128
    f32x4 b2q[4];
#pragma unroll
    for (int i = 0; i < 4; ++i)
        b2q[i] = *(const f32x4*)(b2v + wave * 64 + i * 16 + quad * 4);
    __syncthreads();   // drains phase-0 H writes (lgkm) + Wb(0) DMA (vmcnt)

    // --- H2^T MFMA loop ---
    f32x4 acc2[4][4];
#pragma unroll
    for (int i = 0; i < 4; ++i)
#pragma unroll
        for (int ms = 0; ms < 4; ++ms) acc2[i][ms] = (f32x4){0.f, 0.f, 0.f, 0.f};
#pragma unroll
    for (int s = 0; s < 8; ++s) {
        const int cur = s & 1;
        if (s < 7) stageW(cur ^ 1, s + 1);
        short8 wf[4], hf[4];
#pragma unroll
        for (int i = 0; i < 4; ++i)
            wf[i] = *(const short8*)(&Wb[cur][(quad * 256 + wave * 64 + i * 16 + ln16) * 8]);
        const int col = (s & 3) * 32 + quad * 8;    // k within current half
#pragma unroll
        for (int ms = 0; ms < 4; ++ms)
            hf[ms] = *(const short8*)(&Hh[(ms * 16 + ln16) * HSPLIT + col]);
#pragma unroll
        for (int i = 0; i < 4; ++i)
#pragma unroll
            for (int ms = 0; ms < 4; ++ms)
                acc2[i][ms] = __builtin_amdgcn_mfma_f32_16x16x32_bf16(wf[i], hf[ms], acc2[i][ms], 0, 0, 0);
        if (s == 3) {
            __syncthreads();          // drain DMA(4); phase-0 H reads done
            if (wave >= 2) computeH1_write();   // phase-1: recompute k>=128
            barrier_lds();            // phase-1 visible (lgkm only)
        } else if (s < 7) {
            __syncthreads();          // drain DMA(s+1)
        }
    }

    // --- F gather (late) ---
    const short* Fb = F + (long)b * 4096 * FROW;
    sv4 fv[4][4];
#pragma unroll
    for (int ms = 0; ms < 4; ++ms) {
        int linm = __shfl(lin, ms * 16 + ln16, 64);
        const short* Fr = Fb + (long)linm * FROW + wave * 64 + quad * 4;
#pragma unroll
        for (int i = 0; i < 4; ++i) fv[ms][i] = *(const sv4*)(Fr + i * 16);
    }
    const float fbv = bf2f(Fb[(long)lin * FROW + 256]);

    // --- combine: pred[m] += relu(H2[n][m]+b2[n]) * F[lin[m]][n] ---
    float part[4] = {0.f, 0.f, 0.f, 0.f};
#pragma unroll
    for (int i = 0; i < 4; ++i)
#pragma unroll
        for (int ms = 0; ms < 4; ++ms)
#pragma unroll
            for (int r = 0; r < 4; ++r)
                part[ms] = fmaf(fmaxf(acc2[i][ms][r] + b2q[i][r], 0.f), bf2f(fv[ms][i][r]), part[ms]);
#pragma unroll
    for (int ms = 0; ms < 4; ++ms) {
        part[ms] += __shfl_xor(part[ms], 16, 64);
        part[ms] += __shfl_xor(part[ms], 32, 64);
    }
    if (quad == 0) {
#pragma unroll
        for (int ms = 0; ms < 4; ++ms) red_s[ms * 16 + ln16][wave] = part[ms];
    }
    barrier_lds();
    if (t < 64)
        out[qbase + t] = red_s[t][0] + red_s[t][1] + red_s[t][2] + red_s[t][3] + fbv;
}

// ---------------------------------------------------------------------------
extern "C" void kernel_launch(void* const* d_in, const int* in_sizes, int n_in,
                              void* d_out, int out_size, void* d_ws, size_t ws_size,
                              hipStream_t stream) {
    const float* feat  = (const float*)d_in[0];
    const float* coord = (const float*)d_in[1];
    const float* cell  = (const float*)d_in[2];
    const float* w1    = (const float*)d_in[3];
    const float* b1    = (const float*)d_in[4];
    const float* w2    = (const float*)d_in[5];
    const float* b2    = (const float*)d_in[6];
    const float* w3    = (const float*)d_in[7];
    const float* b3    = (const float*)d_in[8];
    float* out = (float*)d_out;

    char* ws = (char*)d_ws;
    short* w3cB  = (short*)(ws);                       // 72*2176*2      = 313,344
    short* w2cB  = (short*)(ws + 313344);              // 32*2048*2      = 131,072
    short* featT = (short*)(ws + 444416);              // 16*66*66*64*2  = 8,921,088
    short* F     = (short*)(ws + 9365504);             // 16*4096*264*2  = 34,603,008
    (void)ws_size; (void)in_sizes; (void)n_in; (void)out_size;

    prep_transpose_k<<<BB * HT, 256, 0, stream>>>(feat, w2, w3, b3, featT, w3cB, w2cB);
    conv_k<<<BB * HH, 256, 0, stream>>>(featT, w3cB, F);
    mlp_k<<<(BB * QQ) / 64, 256, 0, stream>>>(coord, cell, w1, b1, b2, w2cB, F, out);
}